// Round 10
// baseline (700.524 us; speedup 1.0000x reference)
//
#include <hip/hip_runtime.h>
#include <hip/hip_bf16.h>

#define Bq 2
#define Sq 2048
#define Hq 16
#define CHUNK 64
#define NC 32

typedef __attribute__((ext_vector_type(8))) short short8;  // 8 bf16
typedef __attribute__((ext_vector_type(4))) float f32x4;
typedef unsigned short ushort_t;
typedef unsigned int uint_t;

// Workspace map (bytes):
//   [0, 8388608)            wsAgg  : 1024 chunk-aggregate tiles, bf16, 8KB each
//   [8388608, 9961472)      wsIncl : 32 bh x 3 group-inclusive tiles, fp32, 16KB
//   [9961472, 9961728)      masks  : aggM[32], inclM[32]  (memset to 0 per launch)
#define INCL_OFF_BYTES ((size_t)8388608)
#define MASK_OFF_BYTES ((size_t)9961472)

__device__ inline short f2b(float f) {
  __hip_bfloat16 h = __float2bfloat16(f);
  return *reinterpret_cast<short*>(&h);
}
__device__ inline float b2f(ushort_t s) {
  union { uint_t u; float f; } x{(uint_t)s << 16};
  return x.f;
}
// XOR-swizzled element index for a 64x64 bf16 tile (128B rows, 16B slots).
__device__ inline int swz(int row, int col) {
  return (row << 6) + ((((col >> 3) ^ (row & 7))) << 3) + (col & 7);
}

// ===========================================================================
// Single fused kernel with decoupled-lookback chunk scan.
// Block u = bh*32 + c  (c in LOW bits -> dependency window <= 8 blockIdx).
// ===========================================================================
__global__ __launch_bounds__(256) void fused_lookback_kernel(
    const float* __restrict__ qk, const float* __restrict__ v,
    const float* __restrict__ nrm, ushort_t* __restrict__ wsAgg,
    float* __restrict__ wsIncl, uint_t* __restrict__ aggM,
    uint_t* __restrict__ inclM, float* __restrict__ out) {
  const int u = blockIdx.x;
  const int c = u & 31, h = (u >> 5) & 15, b = u >> 9;
  const int bh = u >> 5;           // 0..63? no: 1024/32 = 32 values (b*16+h)
  const int G = c >> 3;            // 8-chunk group 0..3
  const int t0 = c * CHUNK;
  const int tid = threadIdx.x;
  const int w = tid >> 6, lane = tid & 63, g = lane >> 4, r16 = lane & 15;
  __shared__ short ktS[4096];   // K^T[dk][s], swizzled — persists to phase C
  __shared__ short vtS[4096];   // V^T[dv][s], swizzled — persists to phase C
  __shared__ short msS[4096];   // M_prev bounce
  __shared__ short smS[4096];   // score bounce (per-wave rows)

  // ---- Phase A: stage K^T / V^T (round-6-verified) ----
  {
    const int x = tid & 63, seg = tid >> 6;
    for (int e = 0; e < 2; ++e) {
      const int s0 = seg * 16 + e * 8;
      short8 kb, vb;
#pragma unroll
      for (int j = 0; j < 8; ++j) {
        const size_t t = (size_t)(b * Sq + t0 + s0 + j);
        kb[j] = f2b(qk[((t * 2 + 1) * Hq + h) * 64 + x]);
        vb[j] = f2b(v[(t * Hq + h) * 64 + x]);
      }
      *(short8*)&ktS[swz(x, s0)] = kb;
      *(short8*)&vtS[swz(x, s0)] = vb;
    }
  }
  __syncthreads();

  // ---- chunk aggregate  acc[j][reg] = KV[dv=16w+4g+reg][dk=16j+r16] ----
  short8 vf[2];
#pragma unroll
  for (int kk = 0; kk < 2; ++kk)
    vf[kk] = *(const short8*)&vtS[swz(16 * w + r16, kk * 32 + 8 * g)];
  f32x4 acc[4];
#pragma unroll
  for (int j = 0; j < 4; ++j) {
    acc[j] = f32x4{0.f, 0.f, 0.f, 0.f};
#pragma unroll
    for (int kk = 0; kk < 2; ++kk) {
      short8 kf = *(const short8*)&ktS[swz(16 * j + r16, kk * 32 + 8 * g)];
      acc[j] = __builtin_amdgcn_mfma_f32_16x16x32_bf16(vf[kk], kf, acc[j], 0, 0, 0);
    }
  }

  // ---- publish aggregate (flat per-lane layout: lane tid owns 16 elems) ----
  {
    ushort_t* ap = wsAgg + (size_t)u * 4096 + tid * 16;
    short8 p0, p1;
#pragma unroll
    for (int i = 0; i < 8; ++i) p0[i] = f2b(acc[i >> 2][i & 3]);
#pragma unroll
    for (int i = 8; i < 16; ++i) p1[i - 8] = f2b(acc[i >> 2][i & 3]);
    *(short8*)ap = p0;
    *(short8*)(ap + 8) = p1;
  }
  __threadfence();
  __syncthreads();
  if (tid == 0)
    __hip_atomic_fetch_or(&aggM[bh], 1u << c, __ATOMIC_RELEASE,
                          __HIP_MEMORY_SCOPE_AGENT);

  // ---- lookback: M_prev (exclusive) = incl8[G-1] + aggs [8G, c) ----
  float macc[16];
#pragma unroll
  for (int i = 0; i < 16; ++i) macc[i] = 0.f;
  if (c > 0) {
    if (G > 0) {
      const uint_t bit = 1u << (G - 1);
      int it = 0;
      while (!(__hip_atomic_load(&inclM[bh], __ATOMIC_ACQUIRE,
                                 __HIP_MEMORY_SCOPE_AGENT) & bit)) {
        __builtin_amdgcn_s_sleep(2);
        if (++it > (1 << 22)) break;   // safety valve: never hang the bench
      }
      const float4* ip = (const float4*)(wsIncl + ((size_t)bh * 3 + (G - 1)) * 4096 + tid * 16);
      float4 t0v = ip[0], t1v = ip[1], t2v = ip[2], t3v = ip[3];
      macc[0] += t0v.x;  macc[1] += t0v.y;  macc[2] += t0v.z;  macc[3] += t0v.w;
      macc[4] += t1v.x;  macc[5] += t1v.y;  macc[6] += t1v.z;  macc[7] += t1v.w;
      macc[8] += t2v.x;  macc[9] += t2v.y;  macc[10] += t2v.z; macc[11] += t2v.w;
      macc[12] += t3v.x; macc[13] += t3v.y; macc[14] += t3v.z; macc[15] += t3v.w;
    }
    const uint_t needA = ((1u << c) - (1u << (G * 8)));   // agg bits [8G, c)
    if (needA) {
      int it = 0;
      while ((__hip_atomic_load(&aggM[bh], __ATOMIC_ACQUIRE,
                                __HIP_MEMORY_SCOPE_AGENT) & needA) != needA) {
        __builtin_amdgcn_s_sleep(2);
        if (++it > (1 << 22)) break;
      }
      for (int cp = G * 8; cp < c; ++cp) {
        const ushort_t* ap = wsAgg + ((size_t)(bh * 32 + cp)) * 4096 + tid * 16;
        short8 a0 = *(const short8*)ap;
        short8 a1 = *(const short8*)(ap + 8);
#pragma unroll
        for (int i = 0; i < 8; ++i) {
          macc[i] += b2f((ushort_t)a0[i]);
          macc[8 + i] += b2f((ushort_t)a1[i]);
        }
      }
    }
  }

  // ---- group publisher (c == 8G+7, G<3): inclusive = macc + own agg, fp32 ----
  if ((c & 7) == 7 && G < 3) {
    float* ip = wsIncl + ((size_t)bh * 3 + G) * 4096 + tid * 16;
#pragma unroll
    for (int i = 0; i < 16; ++i) ip[i] = macc[i] + acc[i >> 2][i & 3];
    __threadfence();
    __syncthreads();
    if (tid == 0)
      __hip_atomic_fetch_or(&inclM[bh], 1u << G, __ATOMIC_RELEASE,
                            __HIP_MEMORY_SCOPE_AGENT);
  }

  // ---- bounce macc -> msS [dv][dk] (swizzled), then M fragments ----
#pragma unroll
  for (int j = 0; j < 4; ++j)
#pragma unroll
    for (int reg = 0; reg < 4; ++reg)
      msS[swz(16 * w + 4 * g + reg, 16 * j + r16)] = f2b(macc[j * 4 + reg]);
  __syncthreads();
  short8 mfr[4][2];
#pragma unroll
  for (int j = 0; j < 4; ++j)
#pragma unroll
    for (int kk = 0; kk < 2; ++kk)
      mfr[j][kk] = *(const short8*)&msS[swz(16 * j + r16, kk * 32 + 8 * g)];

  // ---- Phase C (round-6-verified) ----
  const int nk = (w >> 1) + 1;

  float4 kraw[4][4];
#pragma unroll
  for (int j = 0; j < 4; ++j) {
    const size_t s = (size_t)(b * Sq + t0 + 16 * j + r16);
    const float4* kp = (const float4*)(qk + ((s * 2 + 1) * Hq + h) * 64);
#pragma unroll
    for (int p2 = 0; p2 < 2; ++p2) {
      if (j <= w) {   // wave-uniform
        kraw[j][2 * p2]     = kp[8 * p2 + 2 * g];
        kraw[j][2 * p2 + 1] = kp[8 * p2 + 2 * g + 1];
      } else {
        kraw[j][2 * p2]     = make_float4(0.f, 0.f, 0.f, 0.f);
        kraw[j][2 * p2 + 1] = make_float4(0.f, 0.f, 0.f, 0.f);
      }
    }
  }
  float4 qraw[4];
  {
    const size_t t = (size_t)(b * Sq + t0 + 16 * w + r16);
    const float4* qp = (const float4*)(qk + ((t * 2 + 0) * Hq + h) * 64);
#pragma unroll
    for (int p2 = 0; p2 < 2; ++p2) {
      qraw[2 * p2]     = qp[8 * p2 + 2 * g];
      qraw[2 * p2 + 1] = qp[8 * p2 + 2 * g + 1];
    }
  }
  float gn[4];
#pragma unroll
  for (int reg = 0; reg < 4; ++reg)
    gn[reg] = nrm[((size_t)(b * Sq) + t0 + 16 * w + 4 * g + reg) * Hq + h];

  short8 qf[2];
#pragma unroll
  for (int kk = 0; kk < 2; ++kk) {
    float4 a = qraw[2 * kk], bb = qraw[2 * kk + 1];
    short8 qv;
    qv[0] = f2b(a.x);  qv[1] = f2b(a.y);  qv[2] = f2b(a.z);  qv[3] = f2b(a.w);
    qv[4] = f2b(bb.x); qv[5] = f2b(bb.y); qv[6] = f2b(bb.z); qv[7] = f2b(bb.w);
    qf[kk] = qv;
  }

#pragma unroll
  for (int j = 0; j < 4; ++j) {
    f32x4 sacc = {0.f, 0.f, 0.f, 0.f};
#pragma unroll
    for (int kk = 0; kk < 2; ++kk) {
      float4 a = kraw[j][2 * kk], bb = kraw[j][2 * kk + 1];
      short8 kf;
      kf[0] = f2b(a.x);  kf[1] = f2b(a.y);  kf[2] = f2b(a.z);  kf[3] = f2b(a.w);
      kf[4] = f2b(bb.x); kf[5] = f2b(bb.y); kf[6] = f2b(bb.z); kf[7] = f2b(bb.w);
      sacc = __builtin_amdgcn_mfma_f32_16x16x32_bf16(qf[kk], kf, sacc, 0, 0, 0);
    }
    const int scol = 16 * j + r16;
#pragma unroll
    for (int reg = 0; reg < 4; ++reg) {
      const int trow = 16 * w + 4 * g + reg;
      smS[swz(trow, scol)] = (scol <= trow) ? f2b(sacc[reg]) : (short)0;
    }
  }
  asm volatile("s_waitcnt lgkmcnt(0)" ::: "memory");
  __builtin_amdgcn_sched_barrier(0);

  short8 sf0 = *(const short8*)&smS[swz(16 * w + r16, 8 * g)];
  short8 sf1 = short8{};
  if (nk > 1)
    sf1 = *(const short8*)&smS[swz(16 * w + r16, 32 + 8 * g)];

  float gr[4];
#pragma unroll
  for (int reg = 0; reg < 4; ++reg) gr[reg] = __expf(-gn[reg]);

#pragma unroll
  for (int j = 0; j < 4; ++j) {
    f32x4 oacc = {0.f, 0.f, 0.f, 0.f};
    short8 vf0 = *(const short8*)&vtS[swz(16 * j + r16, 8 * g)];
    short8 vf1 = *(const short8*)&vtS[swz(16 * j + r16, 32 + 8 * g)];
    if (nk < 2) vf1 = short8{};
    oacc = __builtin_amdgcn_mfma_f32_16x16x32_bf16(sf0, vf0, oacc, 0, 0, 0);
    oacc = __builtin_amdgcn_mfma_f32_16x16x32_bf16(sf1, vf1, oacc, 0, 0, 0);
    oacc = __builtin_amdgcn_mfma_f32_16x16x32_bf16(qf[0], mfr[j][0], oacc, 0, 0, 0);
    oacc = __builtin_amdgcn_mfma_f32_16x16x32_bf16(qf[1], mfr[j][1], oacc, 0, 0, 0);
    const int dvv = 16 * j + r16;
#pragma unroll
    for (int reg = 0; reg < 4; ++reg) {
      const int trow = 16 * w + 4 * g + reg;
      out[((size_t)(b * Sq + t0 + trow) * Hq + h) * 64 + dvv] =
          gr[reg] * oacc[reg];
    }
  }
}

extern "C" void kernel_launch(void* const* d_in, const int* in_sizes, int n_in,
                              void* d_out, int out_size, void* d_ws, size_t ws_size,
                              hipStream_t stream) {
  const float* qk = (const float*)d_in[0];
  const float* v  = (const float*)d_in[1];
  const float* nn = (const float*)d_in[2];
  float* out = (float*)d_out;
  unsigned char* wsb = (unsigned char*)d_ws;
  ushort_t* wsAgg = (ushort_t*)wsb;
  float* wsIncl = (float*)(wsb + INCL_OFF_BYTES);
  uint_t* aggM = (uint_t*)(wsb + MASK_OFF_BYTES);
  uint_t* inclM = aggM + 32;

  hipMemsetAsync(wsb + MASK_OFF_BYTES, 0, 256, stream);   // reset flags each call
  fused_lookback_kernel<<<1024, 256, 0, stream>>>(qk, v, nn, wsAgg, wsIncl,
                                                  aggM, inclM, out);
}

// Round 11
// 48.331 us; speedup vs baseline: 14.4943x; 14.4943x over previous
//
#include <hip/hip_runtime.h>
#include <hip/hip_bf16.h>

#define Bq 2
#define Sq 2048
#define Hq 16
#define CHUNK 64
#define NC 32

typedef __attribute__((ext_vector_type(8))) short short8;  // 8 bf16
typedef __attribute__((ext_vector_type(4))) float f32x4;
typedef unsigned short ushort_t;
typedef unsigned int uint_t;

// ws map: wsAgg [0, 8388608) : 1024 aggregate tiles, bf16 flat per-lane, 8KB
//         wsV   [8388608, 16777216) : 1024 V^T swizzled bf16 tiles, 8KB
__device__ inline short f2b(float f) {
  __hip_bfloat16 h = __float2bfloat16(f);
  return *reinterpret_cast<short*>(&h);
}
__device__ inline float b2f(ushort_t s) {
  union { uint_t u; float f; } x{(uint_t)s << 16};
  return x.f;
}
// XOR-swizzled element index for a 64x64 bf16 tile (128B rows, 16B slots).
__device__ inline int swz(int row, int col) {
  return (row << 6) + ((((col >> 3) ^ (row & 7))) << 3) + (col & 7);
}

// ---------------------------------------------------------------------------
// Kernel A: stage K^T/V^T (swizzled), dump V^T image to wsV, compute chunk
// aggregate KV tile via MFMA, publish to wsAgg in flat per-lane layout
// (lane tid owns elements [tid*16, tid*16+16); elem i = acc[i>>2][i&3]).
// All pieces verified in rounds 6 (staging, wsV dump) and 10 (flat publish).
// ---------------------------------------------------------------------------
__global__ __launch_bounds__(256) void kv_chunk_kernel(
    const float* __restrict__ qk, const float* __restrict__ v,
    ushort_t* __restrict__ wsAgg, ushort_t* __restrict__ wsV) {
  const int u = blockIdx.x;
  const int c = u & 31, h = (u >> 5) & 15, b = u >> 9;
  const int t0 = c * CHUNK;
  const int tid = threadIdx.x;
  __shared__ short ktS[4096];   // K^T[dk][s], swizzled
  __shared__ short vtS[4096];   // V^T[dv][s], swizzled

  const int x = tid & 63, seg = tid >> 6;
  for (int e = 0; e < 2; ++e) {
    const int s0 = seg * 16 + e * 8;
    short8 kb, vb;
#pragma unroll
    for (int j = 0; j < 8; ++j) {
      const size_t t = (size_t)(b * Sq + t0 + s0 + j);
      kb[j] = f2b(qk[((t * 2 + 1) * Hq + h) * 64 + x]);   // coalesced col read
      vb[j] = f2b(v[(t * Hq + h) * 64 + x]);
    }
    *(short8*)&ktS[swz(x, s0)] = kb;
    *(short8*)&vtS[swz(x, s0)] = vb;
  }
  __syncthreads();

  const int w = tid >> 6, lane = tid & 63, g = lane >> 4, r16 = lane & 15;
  short8 vf[2];
#pragma unroll
  for (int kk = 0; kk < 2; ++kk)
    vf[kk] = *(const short8*)&vtS[swz(16 * w + r16, kk * 32 + 8 * g)];

  // Dump swizzled V^T image (linear 16B stores).
  {
    ushort_t* dvp = wsV + ((size_t)u << 12);
    short8 a0 = *(const short8*)&vtS[tid * 16];
    short8 a1 = *(const short8*)&vtS[tid * 16 + 8];
    *(short8*)(dvp + tid * 16) = a0;
    *(short8*)(dvp + tid * 16 + 8) = a1;
  }

  // Aggregate KV tile: acc[j][reg] = KV[dv=16w+4g+reg][dk=16j+r16].
  f32x4 acc[4];
#pragma unroll
  for (int j = 0; j < 4; ++j) {
    acc[j] = f32x4{0.f, 0.f, 0.f, 0.f};
#pragma unroll
    for (int kk = 0; kk < 2; ++kk) {
      short8 kf = *(const short8*)&ktS[swz(16 * j + r16, kk * 32 + 8 * g)];
      acc[j] = __builtin_amdgcn_mfma_f32_16x16x32_bf16(vf[kk], kf, acc[j], 0, 0, 0);
    }
  }

  // Flat per-lane publish (fully coalesced 16B stores).
  {
    ushort_t* ap = wsAgg + ((size_t)u << 12) + tid * 16;
    short8 p0, p1;
#pragma unroll
    for (int i = 0; i < 8; ++i) p0[i] = f2b(acc[i >> 2][i & 3]);
#pragma unroll
    for (int i = 8; i < 16; ++i) p1[i - 8] = f2b(acc[i >> 2][i & 3]);
    *(short8*)ap = p0;
    *(short8*)(ap + 8) = p1;
  }
}

// ---------------------------------------------------------------------------
// Kernel C: O = gate * ( mask(Q K^T) V + Q M_prev ).
// M_prev = sum of aggregate tiles of chunks [0, c) of this bh — read directly
// from wsAgg (L2/L3-resident), summed in fp32 registers, bounced via LDS to
// MFMA B-fragments (round-10-verified path). Everything else = round 6.
// ---------------------------------------------------------------------------
__global__ __launch_bounds__(256) void attn_out_kernel(
    const float* __restrict__ qk, const float* __restrict__ nrm,
    const ushort_t* __restrict__ wsAgg, const ushort_t* __restrict__ wsV,
    float* __restrict__ out) {
  const int u = blockIdx.x;
  const int c = u & 31, h = (u >> 5) & 15, b = u >> 9;
  const int t0 = c * CHUNK;
  const int tid = threadIdx.x;
  const int w = tid >> 6, lane = tid & 63, g = lane >> 4, r16 = lane & 15;
  __shared__ short msS[4096];   // M_prev bounce
  __shared__ short smS[4096];   // score bounce (per-wave rows)

  const ushort_t* vt = wsV + ((size_t)u << 12);
  const int nk = (w >> 1) + 1;  // live s-tiles per wave: 1,1,2,2

  // ---- independent global loads (issued up front) ----
  short8 vfr[4][2];
#pragma unroll
  for (int kk = 0; kk < 2; ++kk)
#pragma unroll
    for (int j = 0; j < 4; ++j) {
      if (kk < nk)
        vfr[j][kk] = *(const short8*)(vt + swz(16 * j + r16, kk * 32 + 8 * g));
      else
        vfr[j][kk] = short8{};
    }

  float4 kraw[4][4];
#pragma unroll
  for (int j = 0; j < 4; ++j) {
    const size_t s = (size_t)(b * Sq + t0 + 16 * j + r16);
    const float4* kp = (const float4*)(qk + ((s * 2 + 1) * Hq + h) * 64);
#pragma unroll
    for (int p2 = 0; p2 < 2; ++p2) {
      if (j <= w) {   // wave-uniform
        kraw[j][2 * p2]     = kp[8 * p2 + 2 * g];
        kraw[j][2 * p2 + 1] = kp[8 * p2 + 2 * g + 1];
      } else {
        kraw[j][2 * p2]     = make_float4(0.f, 0.f, 0.f, 0.f);
        kraw[j][2 * p2 + 1] = make_float4(0.f, 0.f, 0.f, 0.f);
      }
    }
  }

  float4 qraw[4];
  {
    const size_t t = (size_t)(b * Sq + t0 + 16 * w + r16);
    const float4* qp = (const float4*)(qk + ((t * 2 + 0) * Hq + h) * 64);
#pragma unroll
    for (int p2 = 0; p2 < 2; ++p2) {
      qraw[2 * p2]     = qp[8 * p2 + 2 * g];
      qraw[2 * p2 + 1] = qp[8 * p2 + 2 * g + 1];
    }
  }

  float gn[4];
#pragma unroll
  for (int reg = 0; reg < 4; ++reg)
    gn[reg] = nrm[((size_t)(b * Sq) + t0 + 16 * w + 4 * g + reg) * Hq + h];

  // ---- M_prev: stream-sum aggregate tiles [0, c) (L2-resident) ----
  float macc[16];
#pragma unroll
  for (int i = 0; i < 16; ++i) macc[i] = 0.f;
  {
    const ushort_t* abase = wsAgg + ((size_t)(u - c) << 12) + tid * 16;
    for (int cp = 0; cp < c; ++cp) {
      const ushort_t* ap = abase + ((size_t)cp << 12);
      short8 a0 = *(const short8*)ap;
      short8 a1 = *(const short8*)(ap + 8);
#pragma unroll
      for (int i = 0; i < 8; ++i) {
        macc[i]     += b2f((ushort_t)a0[i]);
        macc[8 + i] += b2f((ushort_t)a1[i]);
      }
    }
  }

  // ---- bounce macc -> msS [dv][dk] swizzled, then M fragments ----
#pragma unroll
  for (int j = 0; j < 4; ++j)
#pragma unroll
    for (int reg = 0; reg < 4; ++reg)
      msS[swz(16 * w + 4 * g + reg, 16 * j + r16)] = f2b(macc[j * 4 + reg]);
  __syncthreads();
  short8 mfr[4][2];
#pragma unroll
  for (int j = 0; j < 4; ++j)
#pragma unroll
    for (int kk = 0; kk < 2; ++kk)
      mfr[j][kk] = *(const short8*)&msS[swz(16 * j + r16, kk * 32 + 8 * g)];

  // ---- scores (round 6 verbatim) ----
  short8 qf[2];
#pragma unroll
  for (int kk = 0; kk < 2; ++kk) {
    float4 a = qraw[2 * kk], bb = qraw[2 * kk + 1];
    short8 qv;
    qv[0] = f2b(a.x);  qv[1] = f2b(a.y);  qv[2] = f2b(a.z);  qv[3] = f2b(a.w);
    qv[4] = f2b(bb.x); qv[5] = f2b(bb.y); qv[6] = f2b(bb.z); qv[7] = f2b(bb.w);
    qf[kk] = qv;
  }

#pragma unroll
  for (int j = 0; j < 4; ++j) {
    f32x4 sacc = {0.f, 0.f, 0.f, 0.f};
#pragma unroll
    for (int kk = 0; kk < 2; ++kk) {
      float4 a = kraw[j][2 * kk], bb = kraw[j][2 * kk + 1];
      short8 kf;
      kf[0] = f2b(a.x);  kf[1] = f2b(a.y);  kf[2] = f2b(a.z);  kf[3] = f2b(a.w);
      kf[4] = f2b(bb.x); kf[5] = f2b(bb.y); kf[6] = f2b(bb.z); kf[7] = f2b(bb.w);
      sacc = __builtin_amdgcn_mfma_f32_16x16x32_bf16(qf[kk], kf, sacc, 0, 0, 0);
    }
    const int scol = 16 * j + r16;
#pragma unroll
    for (int reg = 0; reg < 4; ++reg) {
      const int trow = 16 * w + 4 * g + reg;
      smS[swz(trow, scol)] = (scol <= trow) ? f2b(sacc[reg]) : (short)0;
    }
  }
  asm volatile("s_waitcnt lgkmcnt(0)" ::: "memory");
  __builtin_amdgcn_sched_barrier(0);

  short8 sf0 = *(const short8*)&smS[swz(16 * w + r16, 8 * g)];
  short8 sf1 = short8{};
  if (nk > 1)
    sf1 = *(const short8*)&smS[swz(16 * w + r16, 32 + 8 * g)];

  float gr[4];
#pragma unroll
  for (int reg = 0; reg < 4; ++reg) gr[reg] = __expf(-gn[reg]);

#pragma unroll
  for (int j = 0; j < 4; ++j) {
    f32x4 oacc = {0.f, 0.f, 0.f, 0.f};
    oacc = __builtin_amdgcn_mfma_f32_16x16x32_bf16(sf0, vfr[j][0], oacc, 0, 0, 0);
    oacc = __builtin_amdgcn_mfma_f32_16x16x32_bf16(sf1, vfr[j][1], oacc, 0, 0, 0);
    oacc = __builtin_amdgcn_mfma_f32_16x16x32_bf16(qf[0], mfr[j][0], oacc, 0, 0, 0);
    oacc = __builtin_amdgcn_mfma_f32_16x16x32_bf16(qf[1], mfr[j][1], oacc, 0, 0, 0);
    const int dvv = 16 * j + r16;
#pragma unroll
    for (int reg = 0; reg < 4; ++reg) {
      const int trow = 16 * w + 4 * g + reg;
      out[((size_t)(b * Sq + t0 + trow) * Hq + h) * 64 + dvv] = gr[reg] * oacc[reg];
    }
  }
}

extern "C" void kernel_launch(void* const* d_in, const int* in_sizes, int n_in,
                              void* d_out, int out_size, void* d_ws, size_t ws_size,
                              hipStream_t stream) {
  const float* qk = (const float*)d_in[0];
  const float* v  = (const float*)d_in[1];
  const float* nn = (const float*)d_in[2];
  float* out = (float*)d_out;
  ushort_t* wsAgg = (ushort_t*)d_ws;                 // 8.39MB
  ushort_t* wsV = wsAgg + ((size_t)1024 << 12);      // +8.39MB = 16.78MB total

  kv_chunk_kernel<<<1024, 256, 0, stream>>>(qk, v, wsAgg, wsV);
  attn_out_kernel<<<1024, 256, 0, stream>>>(qk, nn, wsAgg, wsV, out);
}